// Round 2
// 260.222 us; speedup vs baseline: 1.3012x; 1.3012x over previous
//
#include <hip/hip_runtime.h>

#define B_   2
#define H_   16
#define HK_  4
#define G_   4
#define S_   2048
#define D_   128
#define I_   2048

#define BM   128
#define BN   64
#define TPB  256   // 4 waves
#define NIT  (I_ / BN)   // 32

#define LDK  136   // K/U LDS row stride (f16 elems): 128 + 8 pad -> 16B-aligned b128
#define LDV  72    // Vt row stride: 64 + 8 pad
#define LDA  40    // A-scratch row stride: 32 + 8 pad

static constexpr float SCALE = 0.08838834764831845f;  // 1/sqrt(128)

typedef __fp16   p2v __attribute__((ext_vector_type(2)));   // cvt_pkrtz result type
typedef _Float16 h4v __attribute__((ext_vector_type(4)));
typedef _Float16 h8v __attribute__((ext_vector_type(8)));
typedef float    f4v __attribute__((ext_vector_type(4)));

__global__ __launch_bounds__(TPB, 2) void flashmlp_kernel(
    const float* __restrict__ Qg, const float* __restrict__ Kg,
    const float* __restrict__ Ug, const float* __restrict__ Vg,
    float* __restrict__ Og)
{
    // LDS: 2*(64*136) + 128*72 + 128*40 = 31744 f16 = 63488 B  (2 blocks/CU)
    __shared__ _Float16 Ks[BN * LDK];
    __shared__ _Float16 Us[BN * LDK];
    __shared__ _Float16 Vt[D_ * LDV];   // Vt[d][i]  (transposed V tile)
    __shared__ _Float16 As[BM * LDA];   // wave-private rows: no barriers needed around it

    // ---- block decode with XCD swizzle: xcd = bid&7 -> kv-head = xcd>>1
    const int bid   = blockIdx.x;
    const int xcd   = bid & 7;
    const int kh    = xcd >> 1;
    const int j     = ((bid >> 3) << 1) | (xcd & 1);   // 0..127 within head
    const int stile = j & 15;
    const int bg    = j >> 4;          // 0..7
    const int b     = bg >> 2;
    const int g     = bg & 3;
    const int h     = kh * G_ + g;

    const int tid  = threadIdx.x;
    const int wave = tid >> 6;
    const int lane = tid & 63;
    const int m16  = lane & 15;
    const int qq   = lane >> 4;        // 0..3

    const size_t qbase  = ((size_t)(b * H_ + h) * S_ + (size_t)stile * BM) * D_;
    const size_t kvbase = (size_t)kh * I_ * D_;

    // ---- Q fragments (A-operand), f32 -> f16 with SCALE folded in.
    // (Q*s)K == (QK)*s and both M,N use the same scaled Q.
    h8v qf[2][4];
#pragma unroll
    for (int rt = 0; rt < 2; ++rt) {
        const float* qp = Qg + qbase + (size_t)(wave * 32 + rt * 16 + m16) * D_;
#pragma unroll
        for (int ks = 0; ks < 4; ++ks) {
            const float4 a = *(const float4*)(qp + ks * 32 + qq * 8);
            const float4 c = *(const float4*)(qp + ks * 32 + qq * 8 + 4);
            h8v v;
            p2v* v2 = (p2v*)&v;
            v2[0] = __builtin_amdgcn_cvt_pkrtz(a.x * SCALE, a.y * SCALE);
            v2[1] = __builtin_amdgcn_cvt_pkrtz(a.z * SCALE, a.w * SCALE);
            v2[2] = __builtin_amdgcn_cvt_pkrtz(c.x * SCALE, c.y * SCALE);
            v2[3] = __builtin_amdgcn_cvt_pkrtz(c.z * SCALE, c.w * SCALE);
            qf[rt][ks] = v;
        }
    }

    f4v acc_o[2][8];
#pragma unroll
    for (int rt = 0; rt < 2; ++rt)
#pragma unroll
        for (int dt = 0; dt < 8; ++dt)
            acc_o[rt][dt] = f4v{0.f, 0.f, 0.f, 0.f};

    const int sr = tid >> 2;          // K/U staging row 0..63
    const int sc = (tid & 3) * 32;    // K/U staging col base
    const float* kbp = Kg + kvbase + (size_t)sr * D_ + sc;
    const float* ubp = Ug + kvbase + (size_t)sr * D_ + sc;

    // ---- T14 async-stage: K/U tile t+1 prefetched into regs during compute of t.
    float4 kpre[8], upre[8];
#pragma unroll
    for (int g8 = 0; g8 < 8; ++g8) {
        kpre[g8] = *(const float4*)(kbp + g8 * 4);
        upre[g8] = *(const float4*)(ubp + g8 * 4);
    }

    for (int it = 0; it < NIT; ++it) {
        const int i0 = it * BN;

        __syncthreads();  // previous iter's Ks/Us/Vt reads must complete before overwrite

        // ---- V loads for THIS tile: issue first so their latency hides under the
        // K/U cvt+ds_write work below (and under the vmcnt drain of kpre/upre).
        float vpre[8][4];
#pragma unroll
        for (int p = 0; p < 8; ++p) {
            const int idx = p * TPB + tid;
            const int d   = idx & 127;
            const int iq  = idx >> 7;   // 0..15
            const float* vp = Vg + kvbase + (size_t)(i0 + iq * 4) * D_ + d;
            vpre[p][0] = vp[0];
            vpre[p][1] = vp[D_];
            vpre[p][2] = vp[2 * D_];
            vpre[p][3] = vp[3 * D_];
        }

        // ---- K/U: packed cvt + LDS write from the prefetched registers
        {
            h8v kb[4], ub[4];
            p2v* kb2 = (p2v*)kb;
            p2v* ub2 = (p2v*)ub;
#pragma unroll
            for (int g8 = 0; g8 < 8; ++g8) {
                kb2[2 * g8 + 0] = __builtin_amdgcn_cvt_pkrtz(kpre[g8].x, kpre[g8].y);
                kb2[2 * g8 + 1] = __builtin_amdgcn_cvt_pkrtz(kpre[g8].z, kpre[g8].w);
                ub2[2 * g8 + 0] = __builtin_amdgcn_cvt_pkrtz(upre[g8].x, upre[g8].y);
                ub2[2 * g8 + 1] = __builtin_amdgcn_cvt_pkrtz(upre[g8].z, upre[g8].w);
            }
#pragma unroll
            for (int w8 = 0; w8 < 4; ++w8) {
                *(h8v*)(&Ks[sr * LDK + sc + w8 * 8]) = kb[w8];
                *(h8v*)(&Us[sr * LDK + sc + w8 * 8]) = ub[w8];
            }
        }

        // ---- V: packed cvt + transposed LDS write
#pragma unroll
        for (int p = 0; p < 8; ++p) {
            const int idx = p * TPB + tid;
            const int d   = idx & 127;
            const int iq  = idx >> 7;
            h4v w;
            p2v* w2 = (p2v*)&w;
            w2[0] = __builtin_amdgcn_cvt_pkrtz(vpre[p][0], vpre[p][1]);
            w2[1] = __builtin_amdgcn_cvt_pkrtz(vpre[p][2], vpre[p][3]);
            *(h4v*)(&Vt[d * LDV + iq * 4]) = w;
        }

        __syncthreads();

        // ---- issue K/U prefetch for tile t+1 NOW; completes during the MFMA phase,
        // so the conservative vmcnt drain at the next barrier is already satisfied.
        if (it + 1 < NIT) {
            const float* kp = kbp + (size_t)(it + 1) * BN * D_;
            const float* up = ubp + (size_t)(it + 1) * BN * D_;
#pragma unroll
            for (int g8 = 0; g8 < 8; ++g8) {
                kpre[g8] = *(const float4*)(kp + g8 * 4);
                upre[g8] = *(const float4*)(up + g8 * 4);
            }
        }

        // ---- M = Q K^T, N = Q U^T, gated per 16-col tile (keeps live f32 acc small:
        // am/an are 16 regs instead of 64, freeing room for the prefetch registers)
        _Float16 ag[2][4][4];
#pragma unroll
        for (int ct = 0; ct < 4; ++ct) {
            f4v am[2], an[2];
            am[0] = f4v{0.f, 0.f, 0.f, 0.f}; am[1] = am[0];
            an[0] = am[0]; an[1] = am[0];
            __builtin_amdgcn_s_setprio(1);
#pragma unroll
            for (int ks = 0; ks < 4; ++ks) {
                const h8v kf = *(const h8v*)(&Ks[(ct * 16 + m16) * LDK + ks * 32 + qq * 8]);
                const h8v uf = *(const h8v*)(&Us[(ct * 16 + m16) * LDK + ks * 32 + qq * 8]);
                am[0] = __builtin_amdgcn_mfma_f32_16x16x32_f16(qf[0][ks], kf, am[0], 0, 0, 0);
                am[1] = __builtin_amdgcn_mfma_f32_16x16x32_f16(qf[1][ks], kf, am[1], 0, 0, 0);
                an[0] = __builtin_amdgcn_mfma_f32_16x16x32_f16(qf[0][ks], uf, an[0], 0, 0, 0);
                an[1] = __builtin_amdgcn_mfma_f32_16x16x32_f16(qf[1][ks], uf, an[1], 0, 0, 0);
            }
            __builtin_amdgcn_s_setprio(0);
            // gate: A = silu(M) * N   (SCALE already folded into Q)
#pragma unroll
            for (int rt = 0; rt < 2; ++rt)
#pragma unroll
                for (int r = 0; r < 4; ++r) {
                    const float mv = am[rt][r];
                    const float nv = an[rt][r];
                    const float sg = __builtin_amdgcn_rcpf(1.f + __expf(-mv));
                    ag[rt][ct][r] = (_Float16)(mv * sg * nv);
                }
        }

        // ---- O += A V, two 32-col halves through wave-private As (no barriers:
        // each wave writes & reads only rows [wave*32, wave*32+32))
#pragma unroll
        for (int hh = 0; hh < 2; ++hh) {
#pragma unroll
            for (int c2 = 0; c2 < 2; ++c2) {
                const int ct = hh * 2 + c2;
#pragma unroll
                for (int rt = 0; rt < 2; ++rt)
#pragma unroll
                    for (int r = 0; r < 4; ++r)
                        As[(wave * 32 + rt * 16 + qq * 4 + r) * LDA + c2 * 16 + m16] = ag[rt][ct][r];
            }
#pragma unroll
            for (int rt = 0; rt < 2; ++rt) {
                const h8v af = *(const h8v*)(&As[(wave * 32 + rt * 16 + m16) * LDA + qq * 8]);
                __builtin_amdgcn_s_setprio(1);
#pragma unroll
                for (int dt = 0; dt < 8; ++dt) {
                    const h8v vf = *(const h8v*)(&Vt[(dt * 16 + m16) * LDV + hh * 32 + qq * 8]);
                    acc_o[rt][dt] = __builtin_amdgcn_mfma_f32_16x16x32_f16(af, vf, acc_o[rt][dt], 0, 0, 0);
                }
                __builtin_amdgcn_s_setprio(0);
            }
        }
    }

    // ---- epilogue: C-layout -> global fp32
#pragma unroll
    for (int rt = 0; rt < 2; ++rt) {
#pragma unroll
        for (int r = 0; r < 4; ++r) {
            const int row = stile * BM + wave * 32 + rt * 16 + qq * 4 + r;
            float* op = Og + ((size_t)(b * H_ + h) * S_ + row) * D_;
#pragma unroll
            for (int dt = 0; dt < 8; ++dt)
                op[dt * 16 + m16] = acc_o[rt][dt][r];
        }
    }
}

extern "C" void kernel_launch(void* const* d_in, const int* in_sizes, int n_in,
                              void* d_out, int out_size, void* d_ws, size_t ws_size,
                              hipStream_t stream) {
    const float* Q = (const float*)d_in[0];
    const float* K = (const float*)d_in[1];
    const float* U = (const float*)d_in[2];
    const float* V = (const float*)d_in[3];
    float* out = (float*)d_out;

    const int grid = (S_ / BM) * B_ * H_;   // 512 blocks, all co-resident at 2/CU
    flashmlp_kernel<<<dim3(grid), dim3(TPB), 0, stream>>>(Q, K, U, V, out);
}

// Round 3
// 251.903 us; speedup vs baseline: 1.3441x; 1.0330x over previous
//
#include <hip/hip_runtime.h>

#define B_   2
#define H_   16
#define G_   4
#define S_   2048
#define D_   128
#define I_   2048

#define BM   128
#define BN   64
#define TPB  256   // 4 waves
#define NIT  (I_ / BN)   // 32

#define LDA  40    // A-scratch row stride: 32 + 8 pad (80B = 5*16B, keeps b128 reads aligned)

// T2 XOR-swizzle: permute 8-elem (16B) groups within a row by row&7.
// Applied identically on write and read (both sides are register-staged).
#define KIDX(r,c) ((r)*128 + ((c) ^ (((r)&7)<<3)))   // Ks/Us: [64][128] f16, no pad
#define VIDX(d,c) ((d)*64  + ((c) ^ (((d)&7)<<3)))   // Vt:    [128][64] f16, no pad

static constexpr float SCALE = 0.08838834764831845f;  // 1/sqrt(128)

typedef __fp16   p2v __attribute__((ext_vector_type(2)));   // cvt_pkrtz result type
typedef _Float16 h8v __attribute__((ext_vector_type(8)));
typedef float    f4v __attribute__((ext_vector_type(4)));

__global__ __launch_bounds__(TPB, 2) void flashmlp_kernel(
    const float* __restrict__ Qg, const float* __restrict__ Kg,
    const float* __restrict__ Ug, const float* __restrict__ Vg,
    float* __restrict__ Og)
{
    // LDS: (2*64*128 + 128*64 + 128*40) f16 = 29696 f16 = 59392 B (2 blocks/CU)
    __shared__ _Float16 Ks[BN * 128];
    __shared__ _Float16 Us[BN * 128];
    __shared__ _Float16 Vt[D_ * 64];    // Vt[d][i] (transposed V tile), swizzled
    __shared__ _Float16 As[BM * LDA];   // wave-private rows: no barriers needed around it

    // ---- block decode with XCD swizzle: xcd = bid&7 -> kv-head = xcd>>1
    const int bid   = blockIdx.x;
    const int xcd   = bid & 7;
    const int kh    = xcd >> 1;
    const int j     = ((bid >> 3) << 1) | (xcd & 1);   // 0..127 within head
    const int stile = j & 15;
    const int bg    = j >> 4;          // 0..7
    const int b     = bg >> 2;
    const int g     = bg & 3;
    const int h     = kh * G_ + g;

    const int tid  = threadIdx.x;
    const int wave = tid >> 6;
    const int lane = tid & 63;
    const int m16  = lane & 15;
    const int qq   = lane >> 4;        // 0..3

    const size_t qbase  = ((size_t)(b * H_ + h) * S_ + (size_t)stile * BM) * D_;
    const size_t kvbase = (size_t)kh * I_ * D_;

    // ---- Q fragments (A-operand), f32 -> f16 with SCALE folded in.
    h8v qf[2][4];
#pragma unroll
    for (int rt = 0; rt < 2; ++rt) {
        const float* qp = Qg + qbase + (size_t)(wave * 32 + rt * 16 + m16) * D_;
#pragma unroll
        for (int ks = 0; ks < 4; ++ks) {
            const float4 a = *(const float4*)(qp + ks * 32 + qq * 8);
            const float4 c = *(const float4*)(qp + ks * 32 + qq * 8 + 4);
            h8v v;
            p2v* v2 = (p2v*)&v;
            v2[0] = __builtin_amdgcn_cvt_pkrtz(a.x * SCALE, a.y * SCALE);
            v2[1] = __builtin_amdgcn_cvt_pkrtz(a.z * SCALE, a.w * SCALE);
            v2[2] = __builtin_amdgcn_cvt_pkrtz(c.x * SCALE, c.y * SCALE);
            v2[3] = __builtin_amdgcn_cvt_pkrtz(c.z * SCALE, c.w * SCALE);
            qf[rt][ks] = v;
        }
    }

    f4v acc_o[2][8];
#pragma unroll
    for (int rt = 0; rt < 2; ++rt)
#pragma unroll
        for (int dt = 0; dt < 8; ++dt)
            acc_o[rt][dt] = f4v{0.f, 0.f, 0.f, 0.f};

    const int sr = tid >> 2;          // K/U staging row 0..63
    const int sc = (tid & 3) * 32;    // K/U staging col base
    const float* kbp = Kg + kvbase + (size_t)sr * D_ + sc;
    const float* ubp = Ug + kvbase + (size_t)sr * D_ + sc;

    // ---- T14 async-stage: K/U tile t+1 prefetched into regs during compute of t.
    float4 kpre[8], upre[8];
#pragma unroll
    for (int g8 = 0; g8 < 8; ++g8) {
        kpre[g8] = *(const float4*)(kbp + g8 * 4);
        upre[g8] = *(const float4*)(ubp + g8 * 4);
    }

    for (int it = 0; it < NIT; ++it) {
        const int i0 = it * BN;

        __syncthreads();  // previous iter's Ks/Us/Vt reads must complete before overwrite

        // ---- V loads for THIS tile: issue first so their latency hides under the
        // K/U cvt+ds_write work below. Thread owns (d, io): 8 i-elems of one d row.
        float vtmp[4][8];
#pragma unroll
        for (int p = 0; p < 4; ++p) {
            const int idx = p * TPB + tid;
            const int d   = idx & 127;
            const int io  = idx >> 7;   // 0..7
            const float* vp = Vg + kvbase + (size_t)(i0 + io * 8) * D_ + d;
#pragma unroll
            for (int jj = 0; jj < 8; ++jj)
                vtmp[p][jj] = vp[(size_t)jj * D_];
        }

        // ---- K/U: packed cvt + swizzled LDS write from the prefetched registers
        {
            h8v kb[4], ub[4];
            p2v* kb2 = (p2v*)kb;
            p2v* ub2 = (p2v*)ub;
#pragma unroll
            for (int g8 = 0; g8 < 8; ++g8) {
                kb2[2 * g8 + 0] = __builtin_amdgcn_cvt_pkrtz(kpre[g8].x, kpre[g8].y);
                kb2[2 * g8 + 1] = __builtin_amdgcn_cvt_pkrtz(kpre[g8].z, kpre[g8].w);
                ub2[2 * g8 + 0] = __builtin_amdgcn_cvt_pkrtz(upre[g8].x, upre[g8].y);
                ub2[2 * g8 + 1] = __builtin_amdgcn_cvt_pkrtz(upre[g8].z, upre[g8].w);
            }
#pragma unroll
            for (int w8 = 0; w8 < 4; ++w8) {
                *(h8v*)(&Ks[KIDX(sr, sc + w8 * 8)]) = kb[w8];
                *(h8v*)(&Us[KIDX(sr, sc + w8 * 8)]) = ub[w8];
            }
        }

        // ---- V: packed cvt + swizzled transposed write (one 16B chunk per thread per p)
#pragma unroll
        for (int p = 0; p < 4; ++p) {
            const int idx = p * TPB + tid;
            const int d   = idx & 127;
            const int io  = idx >> 7;
            h8v w;
            p2v* w2 = (p2v*)&w;
            w2[0] = __builtin_amdgcn_cvt_pkrtz(vtmp[p][0], vtmp[p][1]);
            w2[1] = __builtin_amdgcn_cvt_pkrtz(vtmp[p][2], vtmp[p][3]);
            w2[2] = __builtin_amdgcn_cvt_pkrtz(vtmp[p][4], vtmp[p][5]);
            w2[3] = __builtin_amdgcn_cvt_pkrtz(vtmp[p][6], vtmp[p][7]);
            *(h8v*)(&Vt[VIDX(d, io * 8)]) = w;
        }

        __syncthreads();

        // ---- issue K/U prefetch for tile t+1; completes during the MFMA phase.
        if (it + 1 < NIT) {
            const float* kp = kbp + (size_t)(it + 1) * BN * D_;
            const float* up = ubp + (size_t)(it + 1) * BN * D_;
#pragma unroll
            for (int g8 = 0; g8 < 8; ++g8) {
                kpre[g8] = *(const float4*)(kp + g8 * 4);
                upre[g8] = *(const float4*)(up + g8 * 4);
            }
        }

        // ---- M = Q K^T, N = Q U^T, gated per 16-col tile
        _Float16 ag[2][4][4];
#pragma unroll
        for (int ct = 0; ct < 4; ++ct) {
            f4v am[2], an[2];
            am[0] = f4v{0.f, 0.f, 0.f, 0.f}; am[1] = am[0];
            an[0] = am[0]; an[1] = am[0];
            __builtin_amdgcn_s_setprio(1);
#pragma unroll
            for (int ks = 0; ks < 4; ++ks) {
                const h8v kf = *(const h8v*)(&Ks[KIDX(ct * 16 + m16, ks * 32 + qq * 8)]);
                const h8v uf = *(const h8v*)(&Us[KIDX(ct * 16 + m16, ks * 32 + qq * 8)]);
                am[0] = __builtin_amdgcn_mfma_f32_16x16x32_f16(qf[0][ks], kf, am[0], 0, 0, 0);
                am[1] = __builtin_amdgcn_mfma_f32_16x16x32_f16(qf[1][ks], kf, am[1], 0, 0, 0);
                an[0] = __builtin_amdgcn_mfma_f32_16x16x32_f16(qf[0][ks], uf, an[0], 0, 0, 0);
                an[1] = __builtin_amdgcn_mfma_f32_16x16x32_f16(qf[1][ks], uf, an[1], 0, 0, 0);
            }
            __builtin_amdgcn_s_setprio(0);
            // gate: A = silu(M) * N   (SCALE already folded into Q)
#pragma unroll
            for (int rt = 0; rt < 2; ++rt)
#pragma unroll
                for (int r = 0; r < 4; ++r) {
                    const float mv = am[rt][r];
                    const float nv = an[rt][r];
                    const float sg = __builtin_amdgcn_rcpf(1.f + __expf(-mv));
                    ag[rt][ct][r] = (_Float16)(mv * sg * nv);
                }
        }

        // ---- O += A V, two 32-col halves through wave-private As (no barriers:
        // each wave writes & reads only rows [wave*32, wave*32+32))
#pragma unroll
        for (int hh = 0; hh < 2; ++hh) {
#pragma unroll
            for (int c2 = 0; c2 < 2; ++c2) {
                const int ct = hh * 2 + c2;
#pragma unroll
                for (int rt = 0; rt < 2; ++rt)
#pragma unroll
                    for (int r = 0; r < 4; ++r)
                        As[(wave * 32 + rt * 16 + qq * 4 + r) * LDA + c2 * 16 + m16] = ag[rt][ct][r];
            }
            // Vt fragments hoisted: identical for both rt (halves Vt read traffic)
            h8v vfr[8];
#pragma unroll
            for (int dt = 0; dt < 8; ++dt)
                vfr[dt] = *(const h8v*)(&Vt[VIDX(dt * 16 + m16, hh * 32 + qq * 8)]);
#pragma unroll
            for (int rt = 0; rt < 2; ++rt) {
                const h8v af = *(const h8v*)(&As[(wave * 32 + rt * 16 + m16) * LDA + qq * 8]);
                __builtin_amdgcn_s_setprio(1);
#pragma unroll
                for (int dt = 0; dt < 8; ++dt)
                    acc_o[rt][dt] = __builtin_amdgcn_mfma_f32_16x16x32_f16(af, vfr[dt], acc_o[rt][dt], 0, 0, 0);
                __builtin_amdgcn_s_setprio(0);
            }
        }
    }

    // ---- epilogue: C-layout -> global fp32
#pragma unroll
    for (int rt = 0; rt < 2; ++rt) {
#pragma unroll
        for (int r = 0; r < 4; ++r) {
            const int row = stile * BM + wave * 32 + rt * 16 + qq * 4 + r;
            float* op = Og + ((size_t)(b * H_ + h) * S_ + row) * D_;
#pragma unroll
            for (int dt = 0; dt < 8; ++dt)
                op[dt * 16 + m16] = acc_o[rt][dt][r];
        }
    }
}

extern "C" void kernel_launch(void* const* d_in, const int* in_sizes, int n_in,
                              void* d_out, int out_size, void* d_ws, size_t ws_size,
                              hipStream_t stream) {
    const float* Q = (const float*)d_in[0];
    const float* K = (const float*)d_in[1];
    const float* U = (const float*)d_in[2];
    const float* V = (const float*)d_in[3];
    float* out = (float*)d_out;

    const int grid = (S_ / BM) * B_ * H_;   // 512 blocks, all co-resident at 2/CU
    flashmlp_kernel<<<dim3(grid), dim3(TPB), 0, stream>>>(Q, K, U, V, out);
}